// Round 8
// baseline (74.408 us; speedup 1.0000x reference)
//
#include <hip/hip_runtime.h>
#include <hip/hip_bf16.h>

#define B_ 4
#define N_ 20000
#define D_ 128
#define E_ 100000
#define NT_ 1250     // 16-node tiles (20000/16 exact)
#define GRB_ 50      // greduce blocks

typedef __attribute__((ext_vector_type(8))) short bf16x8;
typedef __attribute__((ext_vector_type(4))) float f32x4;

// ws layout (float units):
// [0]              flag (int)
// [4]              cnt (unsigned)
// [8,12)           qg (B_)
// [128,640)        g (B_ x D_)
// [640,896)        w5f (float2[128]: {w5_i[c], w5_j[c]})
// [1024,9216)      w7f: 2048 x bf16x8 (32 KB), MFMA B-fragment order
// [9216,649216)    gpart[1250][512]
// [649216,729216)  qi (B x N)
// [729216,809216)  qj (B x N)

__global__ __launch_bounds__(256) void k_prep(
    const float* __restrict__ W7, const float* __restrict__ w5,
    const unsigned* __restrict__ ew, int* __restrict__ flag,
    unsigned* __restrict__ cnt, float* __restrict__ g,
    float2* __restrict__ w5f, bf16x8* __restrict__ w7f)
{
    const int bx = blockIdx.x, t = threadIdx.x;
    if (bx == 8) {
        g[t] = 0.f; g[t + 256] = 0.f;
        if (t < 128) w5f[t] = make_float2(w5[D_ + t], w5[2 * D_ + t]);
        if (t == 0) *cnt = 0u;
        if (t < 64) {
            unsigned v = ew[2 * t + 1];      // high words if int64 (all zero)
            unsigned long long any = __ballot(v != 0u);
            if (t == 0) *flag = (any == 0ULL) ? 1 : 0;
        }
        return;
    }
    int f = bx * 256 + t;                    // 0..2047
    int tt = f >> 8, s = (f >> 6) & 3, lane = f & 63;
    int kg = lane >> 4, rc = lane & 15;
    int col = tt * 16 + rc, k0 = s * 32 + kg * 8;
    union { bf16x8 v; __hip_bfloat16 h[8]; } pk;
    #pragma unroll
    for (int m = 0; m < 8; ++m)
        pk.h[m] = __float2bfloat16(W7[(k0 + m) * D_ + col]);
    w7f[f] = pk.v;
}

// No LDS, no barriers, low VGPR: every wave fully independent.
// B-fragments streamed from the L2-hot 32KB w7f table, 2 col-tiles/iter.
__global__ __launch_bounds__(256, 4) void k_main(
    const float* __restrict__ emb, const bf16x8* __restrict__ w7f,
    const float2* __restrict__ w5f, float* __restrict__ gpart,
    float* __restrict__ qi, float* __restrict__ qj)
{
    const int t = threadIdx.x, b = blockIdx.y;
    const int wv = t >> 6, lane = t & 63, rc = lane & 15, kg = lane >> 4;
    const int tile = blockIdx.x * 4 + wv;
    const int tc = (tile < NT_) ? tile : (NT_ - 1);

    // ---- A loads: 8 independent dwordx4, all in flight immediately
    const float4* p = (const float4*)(emb + (size_t)b * N_ * D_)
                      + ((size_t)(tc * 16 + rc)) * 32 + kg * 2;
    float4 a[8];
    #pragma unroll
    for (int s = 0; s < 4; ++s) { a[2*s] = p[s*8]; a[2*s+1] = p[s*8+1]; }

    // ---- w5 pair loads (L2 hot)
    float2 wij[8];
    #pragma unroll
    for (int tt = 0; tt < 8; ++tt) wij[tt] = w5f[tt * 16 + rc];

    // ---- cvt A to bf16 fragments
    bf16x8 pk[4];
    #pragma unroll
    for (int s = 0; s < 4; ++s) {
        union { bf16x8 v; __hip_bfloat16 h[8]; } u;
        float4 x = a[2*s], y = a[2*s+1];
        u.h[0] = __float2bfloat16(x.x); u.h[1] = __float2bfloat16(x.y);
        u.h[2] = __float2bfloat16(x.z); u.h[3] = __float2bfloat16(x.w);
        u.h[4] = __float2bfloat16(y.x); u.h[5] = __float2bfloat16(y.y);
        u.h[6] = __float2bfloat16(y.z); u.h[7] = __float2bfloat16(y.w);
        pk[s] = u.v;
    }

    // ---- g partials first (frees a[]; stores fire-and-forget under MFMA)
    #pragma unroll
    for (int m = 1; m < 16; m <<= 1) {
        #pragma unroll
        for (int i = 0; i < 8; ++i) {
            a[i].x += __shfl_xor(a[i].x, m);
            a[i].y += __shfl_xor(a[i].y, m);
            a[i].z += __shfl_xor(a[i].z, m);
            a[i].w += __shfl_xor(a[i].w, m);
        }
    }
    if (tile < NT_ && rc == 0) {
        float* gp = gpart + (size_t)tile * 512 + b * 128;
        #pragma unroll
        for (int s = 0; s < 4; ++s) {
            int c0 = s * 32 + kg * 8;
            *reinterpret_cast<float4*>(gp + c0)     = a[2*s];
            *reinterpret_cast<float4*>(gp + c0 + 4) = a[2*s+1];
        }
    }

    // ---- col-tile pairs: 8 B-frag loads (32 regs), 8 MFMA, fold into qip/qjp
    float qip[4] = {0,0,0,0}, qjp[4] = {0,0,0,0};
    #pragma unroll 1
    for (int tp = 0; tp < 4; ++tp) {
        const bf16x8* wp = w7f + (2 * tp) * 256 + lane;
        bf16x8 b0[4], b1[4];
        #pragma unroll
        for (int s = 0; s < 4; ++s) { b0[s] = wp[s * 64]; b1[s] = wp[256 + s * 64]; }
        f32x4 ac0 = {}, ac1 = {};
        #pragma unroll
        for (int s = 0; s < 4; ++s) {
            ac0 = __builtin_amdgcn_mfma_f32_16x16x32_bf16(pk[s], b0[s], ac0, 0, 0, 0);
            ac1 = __builtin_amdgcn_mfma_f32_16x16x32_bf16(pk[s], b1[s], ac1, 0, 0, 0);
        }
        const float wi0 = wij[2*tp].x, wj0 = wij[2*tp].y;
        const float wi1 = wij[2*tp+1].x, wj1 = wij[2*tp+1].y;
        #pragma unroll
        for (int r = 0; r < 4; ++r) {
            float p0 = ac0[r], p1 = ac1[r];
            float l0 = (p0 >= 0.f) ? p0 : 0.01f * p0;
            float l1 = (p1 >= 0.f) ? p1 : 0.01f * p1;
            qip[r] += l0 * wi0 + l1 * wi1;
            qjp[r] += l0 * wj0 + l1 * wj1;
        }
    }

    // ---- reduce over rc (cols), store
    #pragma unroll
    for (int m = 1; m < 16; m <<= 1) {
        #pragma unroll
        for (int r = 0; r < 4; ++r) {
            qip[r] += __shfl_xor(qip[r], m);
            qjp[r] += __shfl_xor(qjp[r], m);
        }
    }
    if (tile < NT_ && rc == 0) {
        #pragma unroll
        for (int r = 0; r < 4; ++r) {
            int node = tile * 16 + kg * 4 + r;
            qi[b * N_ + node] = qip[r];
            qj[b * N_ + node] = qjp[r];
        }
    }
}

// gpart reduction (coalesced) + last-block qg/noop compute (fused)
__global__ __launch_bounds__(512) void k_greduce(
    const float* __restrict__ gpart, float* __restrict__ g,
    unsigned* __restrict__ cnt, const float* __restrict__ W6,
    const float* __restrict__ w5, const float* __restrict__ wno,
    float* __restrict__ qg, float* __restrict__ out)
{
    __shared__ float sp[4][B_][D_];
    __shared__ float sr[2][B_], srn[2][B_];
    __shared__ int lastf;

    const int t = threadIdx.x;          // 0..511
    {
        const int c0 = blockIdx.x * 25;
        float s = 0.f;
        #pragma unroll 5
        for (int i = 0; i < 25; ++i)
            s += gpart[(size_t)(c0 + i) * 512 + t];
        atomicAdd(&g[t], s);
    }
    __threadfence();
    __syncthreads();
    if (t == 0) {
        unsigned old = atomicAdd(cnt, 1u);
        lastf = (old == GRB_ - 1) ? 1 : 0;
    }
    __syncthreads();
    if (!lastf) return;
    __threadfence();   // acquire

    const int col = t & 127, q = t >> 7;
    {
        float p[B_] = {0, 0, 0, 0};
        for (int d = q * 32; d < q * 32 + 32; ++d) {
            float w6 = W6[d * D_ + col];
            #pragma unroll
            for (int b = 0; b < B_; ++b) p[b] += g[b * D_ + d] * w6;
        }
        #pragma unroll
        for (int b = 0; b < B_; ++b) sp[q][b][col] = p[b];
    }
    __syncthreads();
    if (t < 128) {
        float vq[B_], vn[B_];
        #pragma unroll
        for (int b = 0; b < B_; ++b) {
            float pp = sp[0][b][t] + sp[1][b][t] + sp[2][b][t] + sp[3][b][t];
            float lr = (pp >= 0.f) ? pp : 0.01f * pp;
            vq[b] = lr * w5[t];
            vn[b] = g[b * D_ + t] * wno[t];
        }
        #pragma unroll
        for (int m = 1; m < 64; m <<= 1) {
            #pragma unroll
            for (int b = 0; b < B_; ++b) {
                vq[b] += __shfl_xor(vq[b], m);
                vn[b] += __shfl_xor(vn[b], m);
            }
        }
        if ((t & 63) == 0) {
            #pragma unroll
            for (int b = 0; b < B_; ++b) { sr[t >> 6][b] = vq[b]; srn[t >> 6][b] = vn[b]; }
        }
    }
    __syncthreads();
    if (t == 0) {
        #pragma unroll
        for (int b = 0; b < B_; ++b) {
            qg[b] = sr[0][b] + sr[1][b];
            out[(size_t)b * (E_ + 1) + E_] = srn[0][b] + srn[1][b];
        }
    }
}

__global__ __launch_bounds__(256) void k_edge(
    const int* __restrict__ edges, const int* __restrict__ flag,
    const float* __restrict__ qg, const float* __restrict__ qi,
    const float* __restrict__ qj, float* __restrict__ out)
{
    int e = blockIdx.x * 256 + threadIdx.x;
    if (e >= E_) return;
    int u, v;
    if (*flag) { int4 w = ((const int4*)edges)[e]; u = w.x; v = w.z; }
    else       { int2 w = ((const int2*)edges)[e]; u = w.x; v = w.y; }
    float q0 = qg[0], q1 = qg[1], q2 = qg[2], q3 = qg[3];
    out[0 * (size_t)(E_ + 1) + e] = q0 + qi[0 * N_ + u] + qj[0 * N_ + v];
    out[1 * (size_t)(E_ + 1) + e] = q1 + qi[1 * N_ + u] + qj[1 * N_ + v];
    out[2 * (size_t)(E_ + 1) + e] = q2 + qi[2 * N_ + u] + qj[2 * N_ + v];
    out[3 * (size_t)(E_ + 1) + e] = q3 + qi[3 * N_ + u] + qj[3 * N_ + v];
}

extern "C" void kernel_launch(void* const* d_in, const int* in_sizes, int n_in,
                              void* d_out, int out_size, void* d_ws, size_t ws_size,
                              hipStream_t stream)
{
    const float* emb   = (const float*)d_in[0];
    const int*   edges = (const int*)d_in[1];
    const float* W6    = (const float*)d_in[2];
    const float* W7    = (const float*)d_in[3];
    const float* w5    = (const float*)d_in[4];
    const float* wno   = (const float*)d_in[5];
    float* out = (float*)d_out;

    float* W = (float*)d_ws;
    int*      flag  = (int*)W;
    unsigned* cnt   = (unsigned*)(W + 4);
    float*    qg    = W + 8;
    float*    g     = W + 128;
    float2*   w5f   = (float2*)(W + 640);
    bf16x8*   w7f   = (bf16x8*)(W + 1024);
    float*    gpart = W + 9216;
    float*    qi    = W + 649216;
    float*    qj    = W + 729216;

    hipLaunchKernelGGL(k_prep, dim3(9), dim3(256), 0, stream,
                       W7, w5, (const unsigned*)edges, flag, cnt, g, w5f, w7f);
    hipLaunchKernelGGL(k_main, dim3(313, B_), dim3(256), 0, stream,
                       emb, w7f, w5f, gpart, qi, qj);
    hipLaunchKernelGGL(k_greduce, dim3(GRB_), dim3(512), 0, stream,
                       gpart, g, cnt, W6, w5, wno, qg, out);
    hipLaunchKernelGGL(k_edge, dim3((E_ + 255) / 256), dim3(256), 0, stream,
                       edges, flag, qg, qi, qj, out);
}

// Round 9
// 41.541 us; speedup vs baseline: 1.7912x; 1.7912x over previous
//
#include <hip/hip_runtime.h>
#include <hip/hip_bf16.h>

#define B_ 4
#define N_ 20000
#define D_ 128
#define E_ 100000
#define TPB_ 5       // tiles per block (32 nodes each)
#define GXM_ 125     // x-blocks: 125*5*32 = 20000 exactly
#define GRB_ 25      // greduce blocks

typedef __attribute__((ext_vector_type(8))) short bf16x8;
typedef __attribute__((ext_vector_type(4))) float f32x4;

// ws layout (float units):
// [0]              flag (int)
// [4]              cnt (unsigned)
// [8,12)           qg (B_)
// [128,640)        g (B_ x D_)
// [640,896)        w5f (float2[128]: {w5_i[c], w5_j[c]})
// [1024,9216)      w7f: 2048 x bf16x8 (32 KB), MFMA B-fragment order
// [9216,73216)     gpart[125][512]  (per-xblock g partials)
// [73216,153216)   qi (B x N)
// [153216,233216)  qj (B x N)

__global__ __launch_bounds__(256) void k_prep(
    const float* __restrict__ W7, const float* __restrict__ w5,
    const unsigned* __restrict__ ew, int* __restrict__ flag,
    unsigned* __restrict__ cnt, float* __restrict__ g,
    float2* __restrict__ w5f, bf16x8* __restrict__ w7f)
{
    const int bx = blockIdx.x, t = threadIdx.x;
    if (bx == 8) {
        g[t] = 0.f; g[t + 256] = 0.f;
        if (t < 128) w5f[t] = make_float2(w5[D_ + t], w5[2 * D_ + t]);
        if (t == 0) *cnt = 0u;
        if (t < 64) {
            unsigned v = ew[2 * t + 1];      // high words if int64 (all zero)
            unsigned long long any = __ballot(v != 0u);
            if (t == 0) *flag = (any == 0ULL) ? 1 : 0;
        }
        return;
    }
    int f = bx * 256 + t;                    // 0..2047
    int tt = f >> 8, s = (f >> 6) & 3, lane = f & 63;
    int kg = lane >> 4, rc = lane & 15;
    int col = tt * 16 + rc, k0 = s * 32 + kg * 8;
    union { bf16x8 v; __hip_bfloat16 h[8]; } pk;
    #pragma unroll
    for (int m = 0; m < 8; ++m)
        pk.h[m] = __float2bfloat16(W7[(k0 + m) * D_ + col]);
    w7f[f] = pk.v;
}

// m97-style double-buffered pipeline: 500 blocks, 5 tiles each, 1 barrier/tile.
// sA XOR-swizzled: slot(row,c') = G(row, c'^(row&7)); staging reg also feeds g.
__global__ __launch_bounds__(256, 2) void k_main(
    const float* __restrict__ emb, const bf16x8* __restrict__ w7f,
    const float2* __restrict__ w5f, float* __restrict__ gpart,
    float* __restrict__ qi, float* __restrict__ qj)
{
    __shared__ float4 sA4[2][1024];     // 2 x 32 rows x 32 float4 (swizzled)
    __shared__ bf16x8 sB[2048];         // W7 fragments: tt*256 + s*64 + lane
    __shared__ float2 sqp[2][2][32];    // [parity][col-half][node] {qi,qj} partials
    __shared__ float4 sgr[8][32];       // g cross-thread reduce

    const int t = threadIdx.x, b = blockIdx.y, bx = blockIdx.x;
    const int lane = t & 63, wv = t >> 6, rc = lane & 15, kg = lane >> 4;
    const int rg = wv & 1, ch = wv >> 1;        // row-group, col-half
    const int v = t >> 5, c16 = t & 31, cswz = c16 ^ v;
    const int rowx32 = (rg * 16 + rc) * 32, rx = rc & 7;
    const float* embB = emb + (size_t)b * N_ * D_;
    const int tile0 = bx * TPB_;

    // ---- prologue: issue tile0 loads, stage sB, write tile0, issue tile1
    float4 rr[4];
    float gx = 0.f, gy = 0.f, gz = 0.f, gw = 0.f;
    {
        const float* tb = embB + (size_t)tile0 * 4096;
        #pragma unroll
        for (int i2 = 0; i2 < 4; ++i2)
            rr[i2] = *(const float4*)(tb + (i2 * 8 + v) * 128 + cswz * 4);
    }
    #pragma unroll
    for (int i2 = 0; i2 < 8; ++i2)
        ((uint4*)sB)[t + 256 * i2] = ((const uint4*)w7f)[t + 256 * i2];

    float2 wij[4];
    #pragma unroll
    for (int n = 0; n < 4; ++n) wij[n] = w5f[(ch * 4 + n) * 16 + rc];

    #pragma unroll
    for (int i2 = 0; i2 < 4; ++i2) {
        sA4[0][(i2 * 8 + v) * 32 + c16] = rr[i2];
        gx += rr[i2].x; gy += rr[i2].y; gz += rr[i2].z; gw += rr[i2].w;
    }
    {
        const float* tb = embB + (size_t)(tile0 + 1) * 4096;
        #pragma unroll
        for (int i2 = 0; i2 < 4; ++i2)
            rr[i2] = *(const float4*)(tb + (i2 * 8 + v) * 128 + cswz * 4);
    }
    __syncthreads();

    // ---- main pipeline
    #pragma unroll
    for (int i = 0; i < TPB_; ++i) {
        const int cur = i & 1;

        if (i + 1 < TPB_) {
            // write next tile's data (regs -> LDS other buffer), fold into g
            #pragma unroll
            for (int i2 = 0; i2 < 4; ++i2) {
                sA4[cur ^ 1][(i2 * 8 + v) * 32 + c16] = rr[i2];
                gx += rr[i2].x; gy += rr[i2].y; gz += rr[i2].z; gw += rr[i2].w;
            }
            if (i + 2 < TPB_) {   // issue tile i+2 loads (fly under compute)
                const float* tb = embB + (size_t)(tile0 + i + 2) * 4096;
                #pragma unroll
                for (int i2 = 0; i2 < 4; ++i2)
                    rr[i2] = *(const float4*)(tb + (i2 * 8 + v) * 128 + cswz * 4);
            }
        }

        // A-fragments from swizzled LDS (conflict-free), cvt to bf16
        bf16x8 pk[4];
        #pragma unroll
        for (int s = 0; s < 4; ++s) {
            const int c0 = s * 8 + kg * 2;
            float4 f0 = sA4[cur][rowx32 + (c0 ^ rx)];
            float4 f1 = sA4[cur][rowx32 + ((c0 + 1) ^ rx)];
            union { bf16x8 w; __hip_bfloat16 h[8]; } u;
            u.h[0] = __float2bfloat16(f0.x); u.h[1] = __float2bfloat16(f0.y);
            u.h[2] = __float2bfloat16(f0.z); u.h[3] = __float2bfloat16(f0.w);
            u.h[4] = __float2bfloat16(f1.x); u.h[5] = __float2bfloat16(f1.y);
            u.h[6] = __float2bfloat16(f1.z); u.h[7] = __float2bfloat16(f1.w);
            pk[s] = u.w;
        }

        // MFMA: 16 rows x 64 cols (this wave's quadrant), K=128
        f32x4 acc[4] = {};
        #pragma unroll
        for (int s = 0; s < 4; ++s)
            #pragma unroll
            for (int n = 0; n < 4; ++n)
                acc[n] = __builtin_amdgcn_mfma_f32_16x16x32_bf16(
                    pk[s], sB[(ch * 4 + n) * 256 + s * 64 + lane], acc[n], 0, 0, 0);

        // epilogue: leaky + dot w5, reduce over rc, stash partials in LDS
        float qip[4] = {0, 0, 0, 0}, qjp[4] = {0, 0, 0, 0};
        #pragma unroll
        for (int n = 0; n < 4; ++n) {
            #pragma unroll
            for (int r = 0; r < 4; ++r) {
                float pv = acc[n][r];
                float lr = (pv >= 0.f) ? pv : 0.01f * pv;
                qip[r] += lr * wij[n].x;
                qjp[r] += lr * wij[n].y;
            }
        }
        #pragma unroll
        for (int m = 1; m < 16; m <<= 1) {
            #pragma unroll
            for (int r = 0; r < 4; ++r) {
                qip[r] += __shfl_xor(qip[r], m);
                qjp[r] += __shfl_xor(qjp[r], m);
            }
        }
        if (rc == 0) {
            #pragma unroll
            for (int r = 0; r < 4; ++r)
                sqp[cur][ch][rg * 16 + kg * 4 + r] = make_float2(qip[r], qjp[r]);
        }

        __syncthreads();   // sA[cur^1] ready, sqp[cur] ready

        if (t < 64) {
            int n = t & 31;
            float2 h0 = sqp[cur][0][n], h1 = sqp[cur][1][n];
            int node = (tile0 + i) * 32 + n;
            if (t < 32) qi[(size_t)b * N_ + node] = h0.x + h1.x;
            else        qj[(size_t)b * N_ + node] = h0.y + h1.y;
        }
    }

    // ---- g finalize: 8 v-groups x 32 cols -> gpart[bx][b][128]
    sgr[v][cswz] = make_float4(gx, gy, gz, gw);
    __syncthreads();
    if (t < 32) {
        float4 s = sgr[0][t];
        #pragma unroll
        for (int v2 = 1; v2 < 8; ++v2) {
            float4 q = sgr[v2][t];
            s.x += q.x; s.y += q.y; s.z += q.z; s.w += q.w;
        }
        ((float4*)gpart)[(bx * 4 + b) * 32 + t] = s;
    }
}

// gpart reduction + last-block qg/noop compute (fused)
__global__ __launch_bounds__(512) void k_greduce(
    const float* __restrict__ gpart, float* __restrict__ g,
    unsigned* __restrict__ cnt, const float* __restrict__ W6,
    const float* __restrict__ w5, const float* __restrict__ wno,
    float* __restrict__ qg, float* __restrict__ out)
{
    __shared__ float sp[4][B_][D_];
    __shared__ float sr[2][B_], srn[2][B_];
    __shared__ int lastf;

    const int t = threadIdx.x;          // 0..511
    {
        float s = 0.f;
        #pragma unroll
        for (int k = 0; k < 5; ++k)
            s += gpart[(size_t)(blockIdx.x * 5 + k) * 512 + t];
        atomicAdd(&g[t], s);
    }
    __threadfence();
    __syncthreads();
    if (t == 0) {
        unsigned old = atomicAdd(cnt, 1u);
        lastf = (old == GRB_ - 1) ? 1 : 0;
    }
    __syncthreads();
    if (!lastf) return;
    __threadfence();   // acquire

    const int col = t & 127, q = t >> 7;
    {
        float p[B_] = {0, 0, 0, 0};
        for (int d = q * 32; d < q * 32 + 32; ++d) {
            float w6 = W6[d * D_ + col];
            #pragma unroll
            for (int b = 0; b < B_; ++b) p[b] += g[b * D_ + d] * w6;
        }
        #pragma unroll
        for (int b = 0; b < B_; ++b) sp[q][b][col] = p[b];
    }
    __syncthreads();
    if (t < 128) {
        float vq[B_], vn[B_];
        #pragma unroll
        for (int b = 0; b < B_; ++b) {
            float pp = sp[0][b][t] + sp[1][b][t] + sp[2][b][t] + sp[3][b][t];
            float lr = (pp >= 0.f) ? pp : 0.01f * pp;
            vq[b] = lr * w5[t];
            vn[b] = g[b * D_ + t] * wno[t];
        }
        #pragma unroll
        for (int m = 1; m < 64; m <<= 1) {
            #pragma unroll
            for (int b = 0; b < B_; ++b) {
                vq[b] += __shfl_xor(vq[b], m);
                vn[b] += __shfl_xor(vn[b], m);
            }
        }
        if ((t & 63) == 0) {
            #pragma unroll
            for (int b = 0; b < B_; ++b) { sr[t >> 6][b] = vq[b]; srn[t >> 6][b] = vn[b]; }
        }
    }
    __syncthreads();
    if (t == 0) {
        #pragma unroll
        for (int b = 0; b < B_; ++b) {
            qg[b] = sr[0][b] + sr[1][b];
            out[(size_t)b * (E_ + 1) + E_] = srn[0][b] + srn[1][b];
        }
    }
}

__global__ __launch_bounds__(256) void k_edge(
    const int* __restrict__ edges, const int* __restrict__ flag,
    const float* __restrict__ qg, const float* __restrict__ qi,
    const float* __restrict__ qj, float* __restrict__ out)
{
    int e = blockIdx.x * 256 + threadIdx.x;
    if (e >= E_) return;
    int u, v;
    if (*flag) { int4 w = ((const int4*)edges)[e]; u = w.x; v = w.z; }
    else       { int2 w = ((const int2*)edges)[e]; u = w.x; v = w.y; }
    float q0 = qg[0], q1 = qg[1], q2 = qg[2], q3 = qg[3];
    out[0 * (size_t)(E_ + 1) + e] = q0 + qi[0 * N_ + u] + qj[0 * N_ + v];
    out[1 * (size_t)(E_ + 1) + e] = q1 + qi[1 * N_ + u] + qj[1 * N_ + v];
    out[2 * (size_t)(E_ + 1) + e] = q2 + qi[2 * N_ + u] + qj[2 * N_ + v];
    out[3 * (size_t)(E_ + 1) + e] = q3 + qi[3 * N_ + u] + qj[3 * N_ + v];
}

extern "C" void kernel_launch(void* const* d_in, const int* in_sizes, int n_in,
                              void* d_out, int out_size, void* d_ws, size_t ws_size,
                              hipStream_t stream)
{
    const float* emb   = (const float*)d_in[0];
    const int*   edges = (const int*)d_in[1];
    const float* W6    = (const float*)d_in[2];
    const float* W7    = (const float*)d_in[3];
    const float* w5    = (const float*)d_in[4];
    const float* wno   = (const float*)d_in[5];
    float* out = (float*)d_out;

    float* W = (float*)d_ws;
    int*      flag  = (int*)W;
    unsigned* cnt   = (unsigned*)(W + 4);
    float*    qg    = W + 8;
    float*    g     = W + 128;
    float2*   w5f   = (float2*)(W + 640);
    bf16x8*   w7f   = (bf16x8*)(W + 1024);
    float*    gpart = W + 9216;
    float*    qi    = W + 73216;
    float*    qj    = W + 153216;

    hipLaunchKernelGGL(k_prep, dim3(9), dim3(256), 0, stream,
                       W7, w5, (const unsigned*)edges, flag, cnt, g, w5f, w7f);
    hipLaunchKernelGGL(k_main, dim3(GXM_, B_), dim3(256), 0, stream,
                       emb, w7f, w5f, gpart, qi, qj);
    hipLaunchKernelGGL(k_greduce, dim3(GRB_), dim3(512), 0, stream,
                       gpart, g, cnt, W6, w5, wno, qg, out);
    hipLaunchKernelGGL(k_edge, dim3((E_ + 255) / 256), dim3(256), 0, stream,
                       edges, flag, qg, qi, qj, out);
}